// Round 21
// baseline (605.607 us; speedup 1.0000x reference)
//
#include <hip/hip_runtime.h>
#include <cmath>

#define Hn 512
#define Wn 512
#define Bn 32
#define BANDS 16
#define BH 32                       // output rows per band
#define NBLK (Bn * BANDS)           // 512 blocks (8 waves = 8 strips each)
#define NT 512

struct GaussW { float g[9]; };

__device__ __forceinline__ void load3(
    const float* __restrict__ pir, const float* __restrict__ pvi,
    const float* __restrict__ pfu, int y, int xs,
    float& a, float& v, float& f)
{
    bool ok = ((unsigned)y < (unsigned)Hn) && ((unsigned)xs < (unsigned)Wn);
    size_t o = ok ? ((size_t)y * Wn + xs) : 0;
    float aa = pir[o], vv = pvi[o], ff = pfu[o];
    a = ok ? aa : 0.f;  v = ok ? vv : 0.f;  f = ok ? ff : 0.f;
}

__device__ __forceinline__ void stage(
    float4* row, int e, float a, float v, float f)
{
    float di = a - f, dv = v - f;
    row[e] = make_float4(a, v, di * di, dv * dv);
}

// horizontal 9-tap from wave-private LDS + in-register vertical update.
// j/emit compile-time after full unroll (rule #20). pd computed at tap
// (2 VALU instead of a b32 LDS read: LDS pipe is the hotter one).
__device__ __forceinline__ void compute_row(
    const float4* row, int lane, int j, bool emit, float mk, const GaussW& gw,
    float* hb_i, float* hb_v, float* ag_i, float* ag_v, float* ag_q,
    float& Sbi, float& Sbv, float& acc)
{
    float bi = 0.f, bv = 0.f, ga = 0.f, gv = 0.f, qd = 0.f;
    #pragma unroll
    for (int i = 0; i < 9; ++i) {
        float4 q = row[lane + i];
        float gg = gw.g[i];
        bi += q.z;  bv += q.w;
        ga = fmaf(gg, q.x, ga);
        gv = fmaf(gg, q.y, gv);
        qd = fmaf(gg, (q.x - q.y) * (q.x + q.y), qd);   // pd = a^2 - v^2
    }
    Sbi += bi - hb_i[j];  hb_i[j] = bi;
    Sbv += bv - hb_v[j];  hb_v[j] = bv;
    float mi = 0.f, mv = 0.f, mq = 0.f;
    const float g8 = gw.g[8];
    #pragma unroll
    for (int s = 0; s < 9; ++s) {
        if (s == j) {
            mi = fmaf(g8, ga, ag_i[j]);
            mv = fmaf(g8, gv, ag_v[j]);
            mq = fmaf(g8, qd, ag_q[j]);
        } else {
            float w = gw.g[(j - s - 1 + 9) % 9];
            ag_i[s] = fmaf(w, ga, ag_i[s]);
            ag_v[s] = fmaf(w, gv, ag_v[s]);
            ag_q[s] = fmaf(w, qd, ag_q[s]);
        }
    }
    ag_i[j] = 0.f; ag_v[j] = 0.f; ag_q[j] = 0.f;
    if (emit) {
        float dvar = mq - (mi - mv) * (mi + mv);
        float m1  = (dvar > 0.f) ? 1.f : 0.f;
        float sel = (m1 + mk > 0.f) ? 1.f : 0.f;
        acc += sel * (Sbi * (1.f / 81.f)) + (1.f - sel) * (Sbv * (1.f / 81.f));
    }
}

// R21: barrier-free wave-private band kernel. Each wave owns a 64-col strip
// with its own 72-col (8 halo) 2-row dbuf LDS ring -> no __syncthreads in
// the main loop (wave-ordered LDS ops + compiler lgkmcnt). 16 waves/CU
// drift independently, overlapping LDS / VALU / HBM streams that R20's 20
// barriers serialized. Cost: 12.5% redundant halo loads (L2-warm).
__global__ __launch_bounds__(NT) void fuse_loss_kernel(
    const float* __restrict__ vis, const float* __restrict__ ir,
    const float* __restrict__ fus, const float* __restrict__ mask,
    float* __restrict__ ws, GaussW gw)
{
    __shared__ float4 s_q[8][2][2][72];   // [wave][buf][row][entry] 36864 B
    __shared__ float  s_part[8];

    const int t    = threadIdx.x;
    const int lane = t & 63;
    const int w    = t >> 6;              // wave id = strip id
    const int img  = blockIdx.x >> 4;
    const int band = blockIdx.x & 15;
    const int Y0   = band * BH;
    const int wbase = w * 64;
    const int xs1 = wbase - 4 + lane;     // staged col, entry = lane
    const int xs2 = wbase + 60 + lane;    // staged col, entry = lane+64
    const bool h2 = (lane < 8);
    const int xo  = wbase + lane;         // output col (always valid)

    const size_t ibase = (size_t)img * (size_t)(Hn * Wn);
    const float* pir = ir  + ibase;
    const float* pvi = vis + ibase;
    const float* pfu = fus + ibase;
    const float* pmk = mask + ibase;

    // vertical state (statically indexed after unroll)
    float hb_i[9], hb_v[9], ag_i[9], ag_v[9], ag_q[9];
    #pragma unroll
    for (int s = 0; s < 9; ++s) {
        hb_i[s] = 0.f; hb_v[s] = 0.f;
        ag_i[s] = 0.f; ag_v[s] = 0.f; ag_q[s] = 0.f;
    }
    float Sbi = 0.f, Sbv = 0.f, acc = 0.f;

    // prologue: rows r=0,1 (y=Y0-4,Y0-3) -> buf0; preload rows r=2,3
    float a1, v1, f1, a2, v2, f2;
    float a1h = 0.f, v1h = 0.f, f1h = 0.f, a2h = 0.f, v2h = 0.f, f2h = 0.f;
    load3(pir, pvi, pfu, Y0 - 4, xs1, a1, v1, f1);
    if (h2) load3(pir, pvi, pfu, Y0 - 4, xs2, a1h, v1h, f1h);
    load3(pir, pvi, pfu, Y0 - 3, xs1, a2, v2, f2);
    if (h2) load3(pir, pvi, pfu, Y0 - 3, xs2, a2h, v2h, f2h);
    stage(&s_q[w][0][0][0], lane, a1, v1, f1);
    if (h2) stage(&s_q[w][0][0][0], lane + 64, a1h, v1h, f1h);
    stage(&s_q[w][0][1][0], lane, a2, v2, f2);
    if (h2) stage(&s_q[w][0][1][0], lane + 64, a2h, v2h, f2h);
    load3(pir, pvi, pfu, Y0 - 2, xs1, a1, v1, f1);
    if (h2) load3(pir, pvi, pfu, Y0 - 2, xs2, a1h, v1h, f1h);
    load3(pir, pvi, pfu, Y0 - 1, xs1, a2, v2, f2);
    if (h2) load3(pir, pvi, pfu, Y0 - 1, xs2, a2h, v2h, f2h);
    float mkA = 0.f, mkB = 0.f;

    #pragma unroll
    for (int p = 0; p < 20; ++p) {
        const int cur = p & 1;
        if (p < 19) {   // stage rows 2p+2, 2p+3 into the other buffer
            float4* r0n = &s_q[w][cur ^ 1][0][0];
            float4* r1n = &s_q[w][cur ^ 1][1][0];
            stage(r0n, lane, a1, v1, f1);
            if (h2) stage(r0n, lane + 64, a1h, v1h, f1h);
            stage(r1n, lane, a2, v2, f2);
            if (h2) stage(r1n, lane + 64, a2h, v2h, f2h);
        }
        if (p < 18) {   // issue loads for rows 2p+4, 2p+5
            load3(pir, pvi, pfu, Y0 + 2 * p,     xs1, a1, v1, f1);
            if (h2) load3(pir, pvi, pfu, Y0 + 2 * p,     xs2, a1h, v1h, f1h);
            load3(pir, pvi, pfu, Y0 + 2 * p + 1, xs1, a2, v2, f2);
            if (h2) load3(pir, pvi, pfu, Y0 + 2 * p + 1, xs2, a2h, v2h, f2h);
        }
        compute_row(&s_q[w][cur][0][0], lane, (2 * p) % 9,     (p >= 4),
                    mkA, gw, hb_i, hb_v, ag_i, ag_v, ag_q, Sbi, Sbv, acc);
        compute_row(&s_q[w][cur][1][0], lane, (2 * p + 1) % 9, (p >= 4),
                    mkB, gw, hb_i, hb_v, ag_i, ag_v, ag_q, Sbi, Sbv, acc);
        if (p >= 3 && p < 19) {   // mask for pair p+1's emit rows
            mkA = pmk[(size_t)(Y0 + 2 * p - 6) * Wn + xo];
            mkB = pmk[(size_t)(Y0 + 2 * p - 5) * Wn + xo];
        }
    }

    // block reduction -> one partial per block
    #pragma unroll
    for (int off = 32; off > 0; off >>= 1)
        acc += __shfl_down(acc, off, 64);
    if (lane == 0) s_part[w] = acc;
    __syncthreads();
    if (t == 0) {
        float s = 0.f;
        #pragma unroll
        for (int i = 0; i < 8; ++i) s += s_part[i];
        ws[blockIdx.x] = s;
    }
}

__global__ __launch_bounds__(256) void reduce_kernel(const float* __restrict__ ws,
                                                     float* __restrict__ out)
{
    __shared__ float sp[4];
    int t = threadIdx.x;
    float v = 0.f;
    for (int i = t; i < NBLK; i += 256) v += ws[i];
    #pragma unroll
    for (int off = 32; off > 0; off >>= 1)
        v += __shfl_down(v, off, 64);
    if ((t & 63) == 0) sp[t >> 6] = v;
    __syncthreads();
    if (t == 0)
        out[0] = (sp[0] + sp[1] + sp[2] + sp[3]) * (1.f / ((float)Bn * Hn * Wn));
}

extern "C" void kernel_launch(void* const* d_in, const int* in_sizes, int n_in,
                              void* d_out, int out_size, void* d_ws, size_t ws_size,
                              hipStream_t stream) {
    const float* vis  = (const float*)d_in[0];
    const float* ir   = (const float*)d_in[1];
    const float* fus  = (const float*)d_in[2];
    const float* mask = (const float*)d_in[3];
    float* out = (float*)d_out;
    float* ws  = (float*)d_ws;

    GaussW gw;
    double g[9], s = 0.0;
    for (int i = 0; i < 9; ++i) {
        int x = i - 4;
        g[i] = exp(-(double)(x * x) / 4.5);
        s += g[i];
    }
    for (int i = 0; i < 9; ++i) gw.g[i] = (float)(g[i] / s);

    fuse_loss_kernel<<<NBLK, NT, 0, stream>>>(vis, ir, fus, mask, ws, gw);
    reduce_kernel<<<1, 256, 0, stream>>>(ws, out);
}

// Round 22
// 43.906 us; speedup vs baseline: 13.7931x; 13.7931x over previous
//
#include <hip/hip_runtime.h>
#include <cmath>

#define Hn 512
#define Wn 512
#define Bn 32
#define BANDS 16
#define BH 32                       // output rows per band
#define NBLK (Bn * BANDS)           // 512 blocks
#define NT 512                      // 1 thread per column

struct GaussW { float g[9]; };

__device__ __forceinline__ void load_row(
    const float* __restrict__ pir, const float* __restrict__ pvi,
    const float* __restrict__ pfu, int y, int x,
    float& a, float& v, float& f)
{
    bool ok = (unsigned)y < (unsigned)Hn;
    size_t o = ok ? ((size_t)y * Wn + x) : 0;
    float aa = pir[o], vv = pvi[o], ff = pfu[o];
    a = ok ? aa : 0.f;  v = ok ? vv : 0.f;  f = ok ? ff : 0.f;
}

__device__ __forceinline__ void stage_row(
    float4* rowq, int x, float a, float v, float f)
{
    float di = a - f, dv = v - f;
    rowq[x + 4] = make_float4(a, v, di * di, dv * dv);
}

// one image row: horizontal 9-tap from LDS + in-register vertical update.
// j, emit are compile-time constants after full unroll (rule #20).
// pd = a^2-v^2 computed at tap (R21-validated): trades 9 b32 LDS reads/row
// for 27 VALU -- R20 budget showed the LDS pipe at ~85% busy, VALU at 33%.
__device__ __forceinline__ void compute_row(
    const float4* rowq, int x, int j, bool emit,
    float mk, const GaussW& gw,
    float* hb_i, float* hb_v, float* ag_i, float* ag_v, float* ag_q,
    float& Sbi, float& Sbv, float& acc)
{
    float bi = 0.f, bv = 0.f, ga = 0.f, gv = 0.f, qd = 0.f;
    #pragma unroll
    for (int i = 0; i < 9; ++i) {
        float4 q = rowq[x + i];
        float gg = gw.g[i];
        bi += q.z;  bv += q.w;
        ga = fmaf(gg, q.x, ga);
        gv = fmaf(gg, q.y, gv);
        qd = fmaf(gg, (q.x - q.y) * (q.x + q.y), qd);   // pd = a^2 - v^2
    }
    // vertical box: telescoping 9-row window
    Sbi += bi - hb_i[j];  hb_i[j] = bi;
    Sbv += bv - hb_v[j];  hb_v[j] = bv;
    // vertical gauss: 9 phase-rotating slots (R6-verified weights)
    float mi = 0.f, mv = 0.f, mq = 0.f;
    const float g8 = gw.g[8];
    #pragma unroll
    for (int s = 0; s < 9; ++s) {
        if (s == j) {
            mi = fmaf(g8, ga, ag_i[j]);
            mv = fmaf(g8, gv, ag_v[j]);
            mq = fmaf(g8, qd, ag_q[j]);
        } else {
            float w = gw.g[(j - s - 1 + 9) % 9];
            ag_i[s] = fmaf(w, ga, ag_i[s]);
            ag_v[s] = fmaf(w, gv, ag_v[s]);
            ag_q[s] = fmaf(w, qd, ag_q[s]);
        }
    }
    ag_i[j] = 0.f; ag_v[j] = 0.f; ag_q[j] = 0.f;
    if (emit) {
        float dvar = mq - (mi - mv) * (mi + mv);   // var_i - var_v (R15-verified)
        float m1  = (dvar > 0.f) ? 1.f : 0.f;
        float sel = (m1 + mk > 0.f) ? 1.f : 0.f;
        acc += sel * (Sbi * (1.f / 81.f)) + (1.f - sel) * (Sbv * (1.f / 81.f));
    }
}

// R22 = R20 (42.7us, proven clean) minus the s_pd plane. R20's counter
// budget: LDS pipe ~43us of 51us profiled (9 b128 + 9 b32 reads/row/wave);
// dropping the b32 stream cuts LDS traffic 20% with zero register growth
// (R21's spill came from +6 staging regs at the 128-VGPR cliff -- avoided).
__global__ __launch_bounds__(NT) void fuse_loss_kernel(
    const float* __restrict__ vis, const float* __restrict__ ir,
    const float* __restrict__ fus, const float* __restrict__ mask,
    float* __restrict__ ws, GaussW gw)
{
    __shared__ __align__(16) float4 s_q[2][2][Wn + 8];   // (a,v,d2i,d2v) 33280 B
    __shared__ float  s_part[8];

    const int t    = threadIdx.x;                 // column x
    const int img  = blockIdx.x >> 4;
    const int band = blockIdx.x & 15;
    const int Y0   = band * BH;
    const size_t ibase = (size_t)img * (size_t)(Hn * Wn);
    const float* pir = ir  + ibase;
    const float* pvi = vis + ibase;
    const float* pfu = fus + ibase;
    const float* pmk = mask + ibase;

    // zero the 4-px horizontal halos once (stage never touches them)
    if (t < 32) {
        int b = (t >> 4) & 1, rr = (t >> 3) & 1, e = t & 7;
        int col = (e < 4) ? e : (Wn + e);         // 0..3, 516..519
        s_q[b][rr][col] = make_float4(0.f, 0.f, 0.f, 0.f);
    }

    // vertical state (all statically indexed after unroll)
    float hb_i[9], hb_v[9], ag_i[9], ag_v[9], ag_q[9];
    #pragma unroll
    for (int s = 0; s < 9; ++s) {
        hb_i[s] = 0.f; hb_v[s] = 0.f;
        ag_i[s] = 0.f; ag_v[s] = 0.f; ag_q[s] = 0.f;
    }
    float Sbi = 0.f, Sbv = 0.f, acc = 0.f;

    // prologue: rows r=0,1 -> buf0; issue loads for rows r=2,3
    float aA, vA, fA, aB, vB, fB;
    load_row(pir, pvi, pfu, Y0 - 4, t, aA, vA, fA);
    load_row(pir, pvi, pfu, Y0 - 3, t, aB, vB, fB);
    stage_row(s_q[0][0], t, aA, vA, fA);
    stage_row(s_q[0][1], t, aB, vB, fB);
    load_row(pir, pvi, pfu, Y0 - 2, t, aA, vA, fA);
    load_row(pir, pvi, pfu, Y0 - 1, t, aB, vB, fB);
    float mkA = 0.f, mkB = 0.f;
    __syncthreads();

    #pragma unroll
    for (int p = 0; p < 20; ++p) {
        const int cur = p & 1;
        // stage rows 2p+2, 2p+3 (preloaded last iter) into the other buffer
        if (p < 19) {
            stage_row(s_q[cur ^ 1][0], t, aA, vA, fA);
            stage_row(s_q[cur ^ 1][1], t, aB, vB, fB);
        }
        // issue loads for rows 2p+4, 2p+5 (consumed next iter)
        if (p < 18) {
            load_row(pir, pvi, pfu, Y0 + 2 * p,     t, aA, vA, fA);
            load_row(pir, pvi, pfu, Y0 + 2 * p + 1, t, aB, vB, fB);
        }
        // compute rows r=2p, 2p+1 from buf[cur]; emit when r>=8
        compute_row(s_q[cur][0], t, (2 * p) % 9,  (p >= 4),
                    mkA, gw, hb_i, hb_v, ag_i, ag_v, ag_q, Sbi, Sbv, acc);
        compute_row(s_q[cur][1], t, (2 * p + 1) % 9, (p >= 4),
                    mkB, gw, hb_i, hb_v, ag_i, ag_v, ag_q, Sbi, Sbv, acc);
        // issue mask loads for pair p+1's emit rows
        if (p >= 3 && p < 19) {
            mkA = pmk[(size_t)(Y0 + 2 * p - 6) * Wn + t];
            mkB = pmk[(size_t)(Y0 + 2 * p - 5) * Wn + t];
        }
        __syncthreads();
    }

    // block reduction -> one partial per block
    #pragma unroll
    for (int off = 32; off > 0; off >>= 1)
        acc += __shfl_down(acc, off, 64);
    if ((t & 63) == 0) s_part[t >> 6] = acc;
    __syncthreads();
    if (t == 0) {
        float s = 0.f;
        #pragma unroll
        for (int i = 0; i < 8; ++i) s += s_part[i];
        ws[blockIdx.x] = s;
    }
}

__global__ __launch_bounds__(256) void reduce_kernel(const float* __restrict__ ws,
                                                     float* __restrict__ out)
{
    __shared__ float sp[4];
    int t = threadIdx.x;
    float v = 0.f;
    for (int i = t; i < NBLK; i += 256) v += ws[i];
    #pragma unroll
    for (int off = 32; off > 0; off >>= 1)
        v += __shfl_down(v, off, 64);
    if ((t & 63) == 0) sp[t >> 6] = v;
    __syncthreads();
    if (t == 0)
        out[0] = (sp[0] + sp[1] + sp[2] + sp[3]) * (1.f / ((float)Bn * Hn * Wn));
}

extern "C" void kernel_launch(void* const* d_in, const int* in_sizes, int n_in,
                              void* d_out, int out_size, void* d_ws, size_t ws_size,
                              hipStream_t stream) {
    const float* vis  = (const float*)d_in[0];
    const float* ir   = (const float*)d_in[1];
    const float* fus  = (const float*)d_in[2];
    const float* mask = (const float*)d_in[3];
    float* out = (float*)d_out;
    float* ws  = (float*)d_ws;

    GaussW gw;
    double g[9], s = 0.0;
    for (int i = 0; i < 9; ++i) {
        int x = i - 4;
        g[i] = exp(-(double)(x * x) / 4.5);
        s += g[i];
    }
    for (int i = 0; i < 9; ++i) gw.g[i] = (float)(g[i] / s);

    fuse_loss_kernel<<<NBLK, NT, 0, stream>>>(vis, ir, fus, mask, ws, gw);
    reduce_kernel<<<1, 256, 0, stream>>>(ws, out);
}